// Round 1
// baseline (1142.400 us; speedup 1.0000x reference)
//
#include <hip/hip_runtime.h>
#include <math.h>

#define RDIM 192
#define FDIM 28

// SH constants (match reference)
#define SH_C0  0.28209479177387814f
#define SH_C1  0.4886025119029199f
#define SH_C2  0.5462742152960396f
#define SH_C20 0.15769578262626154f
#define SH_C22 0.2731371076480198f

__global__ __launch_bounds__(256)
void plenoxel_fwd(const float* __restrict__ points,
                  const float* __restrict__ voxels,
                  float* __restrict__ out_rgb,    // N*3
                  float* __restrict__ out_sigma,  // N
                  int N)
{
    int i = blockIdx.x * 256 + threadIdx.x;
    if (i >= N) return;

    float px = points[3 * i + 0];
    float py = points[3 * i + 1];
    float pz = points[3 * i + 2];

    // c = clip((p/4 + 1) * 0.5 * (R-1), 0, R-1)
    const float A = (RDIM - 1) / 8.0f;     // 23.875
    const float B = (RDIM - 1) * 0.5f;     // 95.5
    const float RM1 = (float)(RDIM - 1);
    float cx = fminf(fmaxf(px * A + B, 0.0f), RM1);
    float cy = fminf(fmaxf(py * A + B, 0.0f), RM1);
    float cz = fminf(fmaxf(pz * A + B, 0.0f), RM1);

    float cx0 = floorf(cx), cy0 = floorf(cy), cz0 = floorf(cz);
    float fx = cx - cx0, fy = cy - cy0, fz = cz - cz0;
    int x0 = (int)cx0, y0 = (int)cy0, z0 = (int)cz0;
    int x1 = min(x0 + 1, RDIM - 1);
    int y1 = min(y0 + 1, RDIM - 1);
    int z1 = min(z0 + 1, RDIM - 1);

    float gx = 1.0f - fx, gy = 1.0f - fy, gz = 1.0f - fz;

    // 8 corner weights (w[z][y][x])
    float w000 = gz * gy * gx;
    float w001 = gz * gy * fx;
    float w010 = gz * fy * gx;
    float w011 = gz * fy * fx;
    float w100 = fz * gy * gx;
    float w101 = fz * gy * fx;
    float w110 = fz * fy * gx;
    float w111 = fz * fy * fx;

    // row base offsets (each row of FDIM floats is 112B, 16B aligned)
    int b000 = ((z0 * RDIM + y0) * RDIM + x0) * FDIM;
    int b001 = ((z0 * RDIM + y0) * RDIM + x1) * FDIM;
    int b010 = ((z0 * RDIM + y1) * RDIM + x0) * FDIM;
    int b011 = ((z0 * RDIM + y1) * RDIM + x1) * FDIM;
    int b100 = ((z1 * RDIM + y0) * RDIM + x0) * FDIM;
    int b101 = ((z1 * RDIM + y0) * RDIM + x1) * FDIM;
    int b110 = ((z1 * RDIM + y1) * RDIM + x0) * FDIM;
    int b111 = ((z1 * RDIM + y1) * RDIM + x1) * FDIM;

    float acc[FDIM];
#pragma unroll
    for (int k = 0; k < FDIM; ++k) acc[k] = 0.0f;

    // accumulate 8 corners, float4-vectorized (7 x float4 per corner row)
#define CORNER(W, BASE)                                                    \
    {                                                                      \
        const float4* __restrict__ src =                                   \
            (const float4*)(voxels + (BASE));                              \
        _Pragma("unroll")                                                  \
        for (int k = 0; k < 7; ++k) {                                      \
            float4 v = src[k];                                             \
            acc[4 * k + 0] += (W) * v.x;                                   \
            acc[4 * k + 1] += (W) * v.y;                                   \
            acc[4 * k + 2] += (W) * v.z;                                   \
            acc[4 * k + 3] += (W) * v.w;                                   \
        }                                                                  \
    }

    CORNER(w000, b000)
    CORNER(w001, b001)
    CORNER(w010, b010)
    CORNER(w011, b011)
    CORNER(w100, b100)
    CORNER(w101, b101)
    CORNER(w110, b110)
    CORNER(w111, b111)
#undef CORNER

    // direction d = p / ||p||
    float inv = rsqrtf(px * px + py * py + pz * pz);
    float dx = px * inv, dy = py * inv, dz = pz * inv;

    float basis[9];
    basis[0] = SH_C0;
    basis[1] = SH_C1 * dy;
    basis[2] = SH_C1 * dz;
    basis[3] = SH_C1 * dx;
    basis[4] = SH_C2 * dx * dy;
    basis[5] = SH_C2 * dy * dz;
    basis[6] = SH_C20 * (3.0f * dz * dz - 1.0f);
    basis[7] = SH_C2 * dx * dz;
    basis[8] = SH_C22 * (dx * dx - dy * dy);

    // rgb[c] = sigmoid(sum_j sh[c][j] * basis[j]); sh[c][j] = acc[1 + 9c + j]
#pragma unroll
    for (int c = 0; c < 3; ++c) {
        float s = 0.0f;
#pragma unroll
        for (int j = 0; j < 9; ++j) {
            s += acc[1 + 9 * c + j] * basis[j];
        }
        out_rgb[3 * i + c] = 1.0f / (1.0f + expf(-s));
    }

    // sigma = softplus(density), stable form
    float x = acc[0];
    out_sigma[i] = fmaxf(x, 0.0f) + log1pf(expf(-fabsf(x)));
}

extern "C" void kernel_launch(void* const* d_in, const int* in_sizes, int n_in,
                              void* d_out, int out_size, void* d_ws, size_t ws_size,
                              hipStream_t stream) {
    const float* points = (const float*)d_in[0];
    const float* voxels = (const float*)d_in[1];
    int N = in_sizes[0] / 3;

    float* out_rgb = (float*)d_out;          // N*3
    float* out_sigma = out_rgb + (size_t)3 * N;  // N

    int blocks = (N + 255) / 256;
    plenoxel_fwd<<<blocks, 256, 0, stream>>>(points, voxels, out_rgb, out_sigma, N);
}

// Round 2
// 354.331 us; speedup vs baseline: 3.2241x; 3.2241x over previous
//
#include <hip/hip_runtime.h>
#include <math.h>

#define RDIM 192
#define FDIM 28
#define PTS_PER_BLOCK 32   // 256 threads, 8 lanes per point

// SH constants (match reference)
#define SH_C0  0.28209479177387814f
#define SH_C1  0.4886025119029199f
#define SH_C2  0.5462742152960396f
#define SH_C20 0.15769578262626154f
#define SH_C22 0.2731371076480198f

__global__ __launch_bounds__(256)
void plenoxel_fwd(const float* __restrict__ points,
                  const float* __restrict__ voxels,
                  float* __restrict__ out_rgb,    // N*3
                  float* __restrict__ out_sigma,  // N
                  int N)
{
    __shared__ float feats[PTS_PER_BLOCK][FDIM];  // 3.5 KB

    const int tid   = threadIdx.x;
    const int group = tid >> 3;   // 0..31 : point within block
    const int f     = tid & 7;    // 0..7  : feature-quad (7 is idle for loads)
    const int p     = blockIdx.x * PTS_PER_BLOCK + group;

    // ---------- phase 1: gather (8 lanes per point, lane f owns quad f) ----
    if (p < N && f < 7) {
        float px = points[3 * p + 0];
        float py = points[3 * p + 1];
        float pz = points[3 * p + 2];

        const float A = (RDIM - 1) / 8.0f;   // 23.875
        const float B = (RDIM - 1) * 0.5f;   // 95.5
        const float RM1 = (float)(RDIM - 1);
        float cx = fminf(fmaxf(px * A + B, 0.0f), RM1);
        float cy = fminf(fmaxf(py * A + B, 0.0f), RM1);
        float cz = fminf(fmaxf(pz * A + B, 0.0f), RM1);

        float cx0 = floorf(cx), cy0 = floorf(cy), cz0 = floorf(cz);
        float fx = cx - cx0, fy = cy - cy0, fz = cz - cz0;
        int x0 = (int)cx0, y0 = (int)cy0, z0 = (int)cz0;
        int x1 = min(x0 + 1, RDIM - 1);
        int y1 = min(y0 + 1, RDIM - 1);
        int z1 = min(z0 + 1, RDIM - 1);

        float gx = 1.0f - fx, gy = 1.0f - fy, gz = 1.0f - fz;

        float w000 = gz * gy * gx;
        float w001 = gz * gy * fx;
        float w010 = gz * fy * gx;
        float w011 = gz * fy * fx;
        float w100 = fz * gy * gx;
        float w101 = fz * gy * fx;
        float w110 = fz * fy * gx;
        float w111 = fz * fy * fx;

        // row base offsets in floats; all divisible by 4 (FDIM=28)
        int b000 = ((z0 * RDIM + y0) * RDIM + x0) * FDIM;
        int b001 = ((z0 * RDIM + y0) * RDIM + x1) * FDIM;
        int b010 = ((z0 * RDIM + y1) * RDIM + x0) * FDIM;
        int b011 = ((z0 * RDIM + y1) * RDIM + x1) * FDIM;
        int b100 = ((z1 * RDIM + y0) * RDIM + x0) * FDIM;
        int b101 = ((z1 * RDIM + y0) * RDIM + x1) * FDIM;
        int b110 = ((z1 * RDIM + y1) * RDIM + x0) * FDIM;
        int b111 = ((z1 * RDIM + y1) * RDIM + x1) * FDIM;

        const float4* __restrict__ src = (const float4*)voxels;

        // 8 independent 16B loads — all in flight together
        float4 v0 = src[(b000 >> 2) + f];
        float4 v1 = src[(b001 >> 2) + f];
        float4 v2 = src[(b010 >> 2) + f];
        float4 v3 = src[(b011 >> 2) + f];
        float4 v4 = src[(b100 >> 2) + f];
        float4 v5 = src[(b101 >> 2) + f];
        float4 v6 = src[(b110 >> 2) + f];
        float4 v7 = src[(b111 >> 2) + f];

        float4 acc;
        acc.x = w000 * v0.x + w001 * v1.x + w010 * v2.x + w011 * v3.x
              + w100 * v4.x + w101 * v5.x + w110 * v6.x + w111 * v7.x;
        acc.y = w000 * v0.y + w001 * v1.y + w010 * v2.y + w011 * v3.y
              + w100 * v4.y + w101 * v5.y + w110 * v6.y + w111 * v7.y;
        acc.z = w000 * v0.z + w001 * v1.z + w010 * v2.z + w011 * v3.z
              + w100 * v4.z + w101 * v5.z + w110 * v6.z + w111 * v7.z;
        acc.w = w000 * v0.w + w001 * v1.w + w010 * v2.w + w011 * v3.w
              + w100 * v4.w + w101 * v5.w + w110 * v6.w + w111 * v7.w;

        *(float4*)&feats[group][4 * f] = acc;
    }

    __syncthreads();

    // ---------- phase 2: SH shading, one thread per point --------------------
    if (tid < PTS_PER_BLOCK) {
        int p2 = blockIdx.x * PTS_PER_BLOCK + tid;
        if (p2 < N) {
            float px = points[3 * p2 + 0];
            float py = points[3 * p2 + 1];
            float pz = points[3 * p2 + 2];

            float inv = rsqrtf(px * px + py * py + pz * pz);
            float dx = px * inv, dy = py * inv, dz = pz * inv;

            float basis[9];
            basis[0] = SH_C0;
            basis[1] = SH_C1 * dy;
            basis[2] = SH_C1 * dz;
            basis[3] = SH_C1 * dx;
            basis[4] = SH_C2 * dx * dy;
            basis[5] = SH_C2 * dy * dz;
            basis[6] = SH_C20 * (3.0f * dz * dz - 1.0f);
            basis[7] = SH_C2 * dx * dz;
            basis[8] = SH_C22 * (dx * dx - dy * dy);

#pragma unroll
            for (int c = 0; c < 3; ++c) {
                float s = 0.0f;
#pragma unroll
                for (int j = 0; j < 9; ++j) {
                    s += feats[tid][1 + 9 * c + j] * basis[j];
                }
                out_rgb[3 * p2 + c] = 1.0f / (1.0f + expf(-s));
            }

            float x = feats[tid][0];
            out_sigma[p2] = fmaxf(x, 0.0f) + log1pf(expf(-fabsf(x)));
        }
    }
}

extern "C" void kernel_launch(void* const* d_in, const int* in_sizes, int n_in,
                              void* d_out, int out_size, void* d_ws, size_t ws_size,
                              hipStream_t stream) {
    const float* points = (const float*)d_in[0];
    const float* voxels = (const float*)d_in[1];
    int N = in_sizes[0] / 3;

    float* out_rgb = (float*)d_out;              // N*3
    float* out_sigma = out_rgb + (size_t)3 * N;  // N

    int blocks = (N + PTS_PER_BLOCK - 1) / PTS_PER_BLOCK;
    plenoxel_fwd<<<blocks, 256, 0, stream>>>(points, voxels, out_rgb, out_sigma, N);
}